// Round 6
// baseline (581.955 us; speedup 1.0000x reference)
//
#include <hip/hip_runtime.h>
#include <math.h>

// B=1024, S=256, D=256 fp32.
// logp[b,s] = -0.5*(D*log2pi + logdet_s + ||L_s^{-1}(x_b-mu_s)||^2)
//
// ws: one 256x256 fp32 matrix M per s (64 MB).
//   k_gram: lower+diag = sp^T sp (MFMA split-3), grid (s,p).
//   k_factor (1024 thr, 16 waves, 104KB LDS, one block per s):
//     for kb=0..3: {ridge; rank-4 micro-Cholesky + scale; rank-8 blocked
//     forward-substitution inversion (8 rounds); TRSM into LDS T panels
//     (mirror store only); trail pairs read T panels (barrier-free rounds),
//     diag pair carried in P panel}; then invcol j=0..2 in-chain at FULL
//     1024-thread width (2x2 micro-tile — R5 ran it at 256 thr = 4x FMA
//     waste) with exact-cover loads; packed (bf16h<<16)|bf16l output.
//   k_maha: y = invL*diff via mfma split-3, grid (s, btile).

#define LOG2PI_D 470.4965290007924f  // 256*log(2*pi)
#define PS 68          // panel row stride (floats)
#define PANEL (64*68)  // panel size (floats)

typedef __attribute__((ext_vector_type(8))) short bf16x8;
typedef __attribute__((ext_vector_type(4))) float f32x4;

__device__ __forceinline__ unsigned bf16rtn(float f) {
  unsigned u = __float_as_uint(f);
  return (u + 0x7FFFu + ((u >> 16) & 1u)) >> 16;
}
__device__ __forceinline__ unsigned packhl(float v) {
  unsigned h = bf16rtn(v);
  float hf = __uint_as_float(h << 16);
  unsigned l = bf16rtn(v - hf);
  return (h << 16) | l;
}

// Gram via MFMA split-3. Col-major scalar loads; pair-packed h/l LDS planes
// (direct bf16x8 b128 fragment reads, zero unpack). Grid (s, p).
__global__ __launch_bounds__(256) void k_gram(const float* __restrict__ sp,
                                              float* __restrict__ L,
                                              float* __restrict__ ridge_out) {
  __shared__ unsigned Hb[4 * 128 * 20];
  unsigned* AH = Hb;
  unsigned* AL = Hb + 128 * 20;
  unsigned* BH = Hb + 2 * 128 * 20;
  unsigned* BL = Hb + 3 * 128 * 20;
  int p = blockIdx.y, s = blockIdx.x;
  int bi = (p ? 128 : 0), bj = (p == 2 ? 128 : 0);
  const float* A = sp + (size_t)s * 65536;
  float* C = L + (size_t)s * 65536;
  int tid = threadIdx.x, w = tid >> 6, lane = tid & 63;
  int q = lane >> 4, n = lane & 15;
  int mt_[2] = {w, 7 - w};
  f32x4 acc[2][8] = {};
  int c = tid & 127, g = tid >> 7;

  float va[16], vb[16];
#pragma unroll
  for (int u = 0; u < 16; ++u) {
    va[u] = A[(size_t)(g * 16 + u) * 256 + bi + c];
    if (p == 1) vb[u] = A[(size_t)(g * 16 + u) * 256 + bj + c];
  }

  for (int ks = 0; ks < 8; ++ks) {
    __syncthreads();
    {
      unsigned hw[8], lw[8];
#pragma unroll
      for (int m = 0; m < 8; ++m) {
        float v0 = va[2 * m], v1 = va[2 * m + 1];
        unsigned h0 = bf16rtn(v0), h1 = bf16rtn(v1);
        float r0 = v0 - __uint_as_float(h0 << 16);
        float r1 = v1 - __uint_as_float(h1 << 16);
        hw[m] = h0 | (h1 << 16);
        lw[m] = bf16rtn(r0) | (bf16rtn(r1) << 16);
      }
      *(uint4*)&AH[c * 20 + g * 8] = make_uint4(hw[0], hw[1], hw[2], hw[3]);
      *(uint4*)&AH[c * 20 + g * 8 + 4] = make_uint4(hw[4], hw[5], hw[6], hw[7]);
      *(uint4*)&AL[c * 20 + g * 8] = make_uint4(lw[0], lw[1], lw[2], lw[3]);
      *(uint4*)&AL[c * 20 + g * 8 + 4] = make_uint4(lw[4], lw[5], lw[6], lw[7]);
      if (p == 1) {
#pragma unroll
        for (int m = 0; m < 8; ++m) {
          float v0 = vb[2 * m], v1 = vb[2 * m + 1];
          unsigned h0 = bf16rtn(v0), h1 = bf16rtn(v1);
          float r0 = v0 - __uint_as_float(h0 << 16);
          float r1 = v1 - __uint_as_float(h1 << 16);
          hw[m] = h0 | (h1 << 16);
          lw[m] = bf16rtn(r0) | (bf16rtn(r1) << 16);
        }
        *(uint4*)&BH[c * 20 + g * 8] = make_uint4(hw[0], hw[1], hw[2], hw[3]);
        *(uint4*)&BH[c * 20 + g * 8 + 4] = make_uint4(hw[4], hw[5], hw[6], hw[7]);
        *(uint4*)&BL[c * 20 + g * 8] = make_uint4(lw[0], lw[1], lw[2], lw[3]);
        *(uint4*)&BL[c * 20 + g * 8 + 4] = make_uint4(lw[4], lw[5], lw[6], lw[7]);
      }
    }
    __syncthreads();
    if (ks < 7) {
      int r0g = (ks + 1) * 32 + g * 16;
#pragma unroll
      for (int u = 0; u < 16; ++u) {
        va[u] = A[(size_t)(r0g + u) * 256 + bi + c];
        if (p == 1) vb[u] = A[(size_t)(r0g + u) * 256 + bj + c];
      }
    }
    const unsigned* TBH = (p == 1) ? BH : AH;
    const unsigned* TBL = (p == 1) ? BL : AL;
    bf16x8 Ah[2], Al[2];
#pragma unroll
    for (int t = 0; t < 2; ++t) {
      int col = mt_[t] * 16 + n;
      Ah[t] = *(const bf16x8*)&AH[col * 20 + q * 4];
      Al[t] = *(const bf16x8*)&AL[col * 20 + q * 4];
    }
    int ntmax = (p == 1) ? 8 : (8 - w);
    for (int nt = 0; nt < ntmax; ++nt) {
      bf16x8 bh = *(const bf16x8*)&TBH[(nt * 16 + n) * 20 + q * 4];
      bf16x8 bl = *(const bf16x8*)&TBL[(nt * 16 + n) * 20 + q * 4];
#pragma unroll
      for (int t = 0; t < 2; ++t) {
        if (p == 1 || nt <= mt_[t]) {
          acc[t][nt] = __builtin_amdgcn_mfma_f32_16x16x32_bf16(Ah[t], bh, acc[t][nt], 0, 0, 0);
          acc[t][nt] = __builtin_amdgcn_mfma_f32_16x16x32_bf16(Ah[t], bl, acc[t][nt], 0, 0, 0);
          acc[t][nt] = __builtin_amdgcn_mfma_f32_16x16x32_bf16(Al[t], bh, acc[t][nt], 0, 0, 0);
        }
      }
    }
  }
  if (p != 1) {
    float dsum = 0.f;
#pragma unroll
    for (int t = 0; t < 2; ++t) {
      if ((n >> 2) == q) dsum += acc[t][mt_[t]][n & 3];
    }
    dsum += __shfl_down(dsum, 32, 64);
    dsum += __shfl_down(dsum, 16, 64);
    dsum += __shfl_down(dsum, 8, 64);
    dsum += __shfl_down(dsum, 4, 64);
    dsum += __shfl_down(dsum, 2, 64);
    dsum += __shfl_down(dsum, 1, 64);
    if (lane == 0) atomicAdd(&ridge_out[s], dsum * (0.01f / 256.0f));
  }
  float* slab = (float*)Hb;
  for (int t = 0; t < 2; ++t) {
    __syncthreads();
#pragma unroll
    for (int nt = 0; nt < 8; ++nt)
#pragma unroll
      for (int r = 0; r < 4; ++r)
        slab[w * 2048 + (q * 4 + r) * 128 + nt * 16 + n] = acc[t][nt][r];
    __syncthreads();
#pragma unroll
    for (int it = 0; it < 8; ++it) {
      int idx = tid + it * 256;
      int row = idx >> 5, c4 = idx & 31;
      int wsrc = row >> 4, r16 = row & 15;
      int rt = t ? (7 - wsrc) : wsrc;
      if (p == 1 || (c4 >> 2) <= rt) {
        int d = bi + rt * 16 + r16;
        *(float4*)(C + (size_t)d * 256 + bj + c4 * 4) =
            *(float4*)&slab[wsrc * 2048 + r16 * 128 + c4 * 4];
      }
    }
  }
}

// Factor chain: one block of 1024 threads per s; T panels LDS-resident.
__global__ __launch_bounds__(1024) void k_factor(float* __restrict__ L,
                                                 const float* __restrict__ ridge_buf) {
  extern __shared__ float lds[];
  float* P = lds;
  float* W = lds + PANEL;
  float* WT = lds + 2 * PANEL;
  int s = blockIdx.x;
  float* M = L + (size_t)s * 65536;
  unsigned* M32 = (unsigned*)M;
  int tid = threadIdx.x;
  int k4 = tid & 15, r64 = tid >> 4;  // exact 64-row cover at 1024 thr
  float ridge = ridge_buf[s];

  for (int kb = 0; kb < 4; ++kb) {
    int base = kb * 64;
    __syncthreads();
    if (kb == 0)
      *(float4*)&P[r64 * PS + k4 * 4] =
          *(const float4*)(M + (size_t)(base + r64) * 256 + base + k4 * 4);
    // kb>0: P carried in LDS from previous kb's diag trail pair.
    __syncthreads();
    if (tid < 64) P[tid * PS + tid] += ridge;
    __syncthreads();
    // ---- rank-4 micro-panel factor (columns stay RAW) ----
    {
      int eo = tid & 63, ro = tid >> 6;  // ro 0..15
      for (int cb = 0; cb < 16; ++cb) {
        int c0 = cb * 4;
        float g00 = P[c0 * PS + c0];
        float g10 = P[(c0 + 1) * PS + c0], g11 = P[(c0 + 1) * PS + c0 + 1];
        float g20 = P[(c0 + 2) * PS + c0], g21 = P[(c0 + 2) * PS + c0 + 1],
              g22 = P[(c0 + 2) * PS + c0 + 2];
        float g30 = P[(c0 + 3) * PS + c0], g31 = P[(c0 + 3) * PS + c0 + 1],
              g32 = P[(c0 + 3) * PS + c0 + 2], g33 = P[(c0 + 3) * PS + c0 + 3];
        float l00 = sqrtf(g00), r0 = 1.f / l00;
        float l10 = g10 * r0, l20 = g20 * r0, l30 = g30 * r0;
        float l11 = sqrtf(g11 - l10 * l10), r1 = 1.f / l11;
        float l21 = (g21 - l20 * l10) * r1, l31 = (g31 - l30 * l10) * r1;
        float l22 = sqrtf(g22 - l20 * l20 - l21 * l21), r2 = 1.f / l22;
        float l32 = (g32 - l30 * l20 - l31 * l21) * r2;
        float l33 = sqrtf(g33 - l30 * l30 - l31 * l31 - l32 * l32), r3 = 1.f / l33;
        int e = c0 + 4 + eo;
        if (e < 64) {
          float p0 = P[e * PS + c0], p1 = P[e * PS + c0 + 1];
          float p2 = P[e * PS + c0 + 2], p3 = P[e * PS + c0 + 3];
          float le0 = p0 * r0;
          float le1 = (p1 - le0 * l10) * r1;
          float le2 = (p2 - le0 * l20 - le1 * l21) * r2;
          float le3 = (p3 - le0 * l30 - le1 * l31 - le2 * l32) * r3;
          for (int r = c0 + 4 + ro; r < 64; r += 16) {
            float q0 = P[r * PS + c0], q1 = P[r * PS + c0 + 1];
            float q2 = P[r * PS + c0 + 2], q3 = P[r * PS + c0 + 3];
            float lr0 = q0 * r0;
            float lr1 = (q1 - lr0 * l10) * r1;
            float lr2 = (q2 - lr0 * l20 - lr1 * l21) * r2;
            float lr3 = (q3 - lr0 * l30 - lr1 * l31 - lr2 * l32) * r3;
            P[r * PS + e] -= lr0 * le0 + lr1 * le1 + lr2 * le2 + lr3 * le3;
          }
        }
        __syncthreads();
      }
    }
    // ---- scale pass ----
    {
      int cb = tid >> 4, lane16 = tid & 15;
      int c0 = cb * 4;
      float vals[4][4];
      int rows[4], nr = 0;
      if (tid < 256) {
        float g00 = P[c0 * PS + c0];
        float g10 = P[(c0 + 1) * PS + c0], g11 = P[(c0 + 1) * PS + c0 + 1];
        float g20 = P[(c0 + 2) * PS + c0], g21 = P[(c0 + 2) * PS + c0 + 1],
              g22 = P[(c0 + 2) * PS + c0 + 2];
        float g30 = P[(c0 + 3) * PS + c0], g31 = P[(c0 + 3) * PS + c0 + 1],
              g32 = P[(c0 + 3) * PS + c0 + 2], g33 = P[(c0 + 3) * PS + c0 + 3];
        float l00 = sqrtf(g00), r0 = 1.f / l00;
        float l10 = g10 * r0, l20 = g20 * r0, l30 = g30 * r0;
        float l11 = sqrtf(g11 - l10 * l10), r1 = 1.f / l11;
        float l21 = (g21 - l20 * l10) * r1, l31 = (g31 - l30 * l10) * r1;
        float l22 = sqrtf(g22 - l20 * l20 - l21 * l21), r2 = 1.f / l22;
        float l32 = (g32 - l30 * l20 - l31 * l21) * r2;
        float l33 = sqrtf(g33 - l30 * l30 - l31 * l31 - l32 * l32), r3 = 1.f / l33;
        for (int r = c0 + lane16; r < 64; r += 16) {
          int i = r - c0;
          if (i == 0) { vals[nr][0] = l00; vals[nr][1] = 0; vals[nr][2] = 0; vals[nr][3] = 0; }
          else if (i == 1) { vals[nr][0] = l10; vals[nr][1] = l11; vals[nr][2] = 0; vals[nr][3] = 0; }
          else if (i == 2) { vals[nr][0] = l20; vals[nr][1] = l21; vals[nr][2] = l22; vals[nr][3] = 0; }
          else if (i == 3) { vals[nr][0] = l30; vals[nr][1] = l31; vals[nr][2] = l32; vals[nr][3] = l33; }
          else {
            float q0 = P[r * PS + c0], q1 = P[r * PS + c0 + 1];
            float q2 = P[r * PS + c0 + 2], q3 = P[r * PS + c0 + 3];
            float lr0 = q0 * r0;
            float lr1 = (q1 - lr0 * l10) * r1;
            float lr2 = (q2 - lr0 * l20 - lr1 * l21) * r2;
            float lr3 = (q3 - lr0 * l30 - lr1 * l31 - lr2 * l32) * r3;
            vals[nr][0] = lr0; vals[nr][1] = lr1; vals[nr][2] = lr2; vals[nr][3] = lr3;
          }
          rows[nr++] = r;
        }
      }
      __syncthreads();
      if (tid < 256) {
        for (int u = 0; u < nr; ++u) {
          int r = rows[u];
          P[r * PS + c0] = vals[u][0];
          P[r * PS + c0 + 1] = vals[u][1];
          P[r * PS + c0 + 2] = vals[u][2];
          P[r * PS + c0 + 3] = vals[u][3];
        }
      }
    }
    __syncthreads();
    // ---- rank-8 blocked forward-substitution inversion: W = inv(P_lower) ----
    for (int idx = tid; idx < PANEL; idx += 1024) W[idx] = 0.f;
    __syncthreads();
    for (int r8 = 0; r8 < 8; ++r8) {
      int k0 = r8 * 8;
      if (tid < 512) {
        int i = tid >> 6, cc = tid & 63;
        int row = k0 + i;
        float ss = 0.f;
        for (int k = 0; k < k0; ++k) ss += P[row * PS + k] * W[k * PS + cc];
        WT[i * PS + cc] = ss;  // WT rows 0..7 as S scratch
      }
      __syncthreads();
      if (tid < 64) {
        int cc = tid;
        float x[8];
#pragma unroll
        for (int m = 0; m < 8; ++m) {
          float v = ((cc == k0 + m) ? 1.f : 0.f) - WT[m * PS + cc];
#pragma unroll
          for (int u = 0; u < 8; ++u)
            if (u < m) v -= P[(k0 + m) * PS + k0 + u] * x[u];
          x[m] = v / P[(k0 + m) * PS + k0 + m];
          W[(k0 + m) * PS + cc] = x[m];
        }
      }
      __syncthreads();
    }
    // WT = W^T (full overwrite of scratch)
    {
      float4 v = *(float4*)&W[r64 * PS + k4 * 4];
      WT[(k4 * 4 + 0) * PS + r64] = v.x;
      WT[(k4 * 4 + 1) * PS + r64] = v.y;
      WT[(k4 * 4 + 2) * PS + r64] = v.z;
      WT[(k4 * 4 + 3) * PS + r64] = v.w;
    }
    __syncthreads();
    // store W (diag block) to M — consumed by invcol + maha
    *(float4*)(M + (size_t)(base + r64) * 256 + base + k4 * 4) = *(float4*)&W[r64 * PS + k4 * 4];
    // ---- TRSM: tiles into LDS T panels; mirror store only ----
    int nrt = 3 - kb;
    for (int rt0 = 0; rt0 < nrt; rt0 += 2) {
      int pr = tid >> 9, t2 = tid & 511;
      int my = rt0 + pr;
      bool act = my < nrt;
      float* Tb = lds + (size_t)(3 + (act ? my : 0)) * PANEL;
      int k42 = t2 & 15, rbl = t2 >> 4;
      int ty2 = t2 >> 4, tx2 = t2 & 15;
      int g0 = base + 64 + my * 64;
      __syncthreads();
      if (act) {
#pragma unroll
        for (int r = rbl; r < 64; r += 32) {
          float4 v = *(const float4*)(M + (size_t)(g0 + r) * 256 + base + k42 * 4);
          Tb[(k42 * 4 + 0) * PS + r] = v.x;
          Tb[(k42 * 4 + 1) * PS + r] = v.y;
          Tb[(k42 * 4 + 2) * PS + r] = v.z;
          Tb[(k42 * 4 + 3) * PS + r] = v.w;
        }
      }
      __syncthreads();
      float acc[2][4] = {};
      if (act) {
        for (int k = 0; k < 64; ++k) {
          float a0 = Tb[k * PS + ty2 * 2], a1 = Tb[k * PS + ty2 * 2 + 1];
          float b[4];
          *(float4*)b = *(float4*)&WT[k * PS + tx2 * 4];
#pragma unroll
          for (int j = 0; j < 4; ++j) {
            acc[0][j] += a0 * b[j];
            acc[1][j] += a1 * b[j];
          }
        }
      }
      __syncthreads();
      if (act) {
        // overwrite Tb with L^T layout [k][m] (trail operand + mirror source)
#pragma unroll
        for (int i = 0; i < 2; ++i)
#pragma unroll
          for (int j = 0; j < 4; ++j) Tb[(tx2 * 4 + j) * PS + ty2 * 2 + i] = acc[i][j];
      }
      __syncthreads();
      if (act) {
#pragma unroll
        for (int r = rbl; r < 64; r += 32)
          *(float4*)(M + (size_t)(base + r) * 256 + g0 + k42 * 4) = *(float4*)&Tb[r * PS + k42 * 4];
      }
      // (row-major lower store dropped — dead: trail reads LDS, maha reads packed)
    }
    __syncthreads();
    // ---- trailing updates: read T panels, barrier-free rounds ----
    int np = ((3 - kb) * (4 - kb)) / 2;
    for (int p0 = 0; p0 < np; p0 += 2) {
      int pr = tid >> 9, t2 = tid & 511;
      int my = p0 + pr;
      bool act = my < np;
      int ti = kb + 1, tj = kb + 1;
      {
        int cnt = 0;
        for (int a = kb + 1; a < 4; ++a)
          for (int b = kb + 1; b <= a; ++b) {
            if (cnt == my) { ti = a; tj = b; }
            ++cnt;
          }
      }
      float* Pi = lds + (size_t)(3 + (ti - kb - 1)) * PANEL;
      float* Pj = lds + (size_t)(3 + (tj - kb - 1)) * PANEL;
      int ty2 = t2 >> 4, tx2 = t2 & 15;
      float acc[2][4];
      if (act) {
#pragma unroll
        for (int i = 0; i < 2; ++i)
          *(float4*)&acc[i][0] =
              *(const float4*)(M + (size_t)(ti * 64 + ty2 * 2 + i) * 256 + tj * 64 + tx2 * 4);
        for (int k = 0; k < 64; ++k) {
          float a0 = Pi[k * PS + ty2 * 2], a1 = Pi[k * PS + ty2 * 2 + 1];
          float b[4];
          *(float4*)b = *(float4*)&Pj[k * PS + tx2 * 4];
#pragma unroll
          for (int j = 0; j < 4; ++j) {
            acc[0][j] -= a0 * b[j];
            acc[1][j] -= a1 * b[j];
          }
        }
        if (ti == tj && ti == kb + 1) {
          // next panel: carry in P (LDS), skip dead M store
#pragma unroll
          for (int i = 0; i < 2; ++i)
            *(float4*)&P[(ty2 * 2 + i) * PS + tx2 * 4] =
                make_float4(acc[i][0], acc[i][1], acc[i][2], acc[i][3]);
        } else {
#pragma unroll
          for (int i = 0; i < 2; ++i)
            *(float4*)(M + (size_t)(ti * 64 + ty2 * 2 + i) * 256 + tj * 64 + tx2 * 4) =
                make_float4(acc[i][0], acc[i][1], acc[i][2], acc[i][3]);
        }
      }
    }
  }

  // ---- invcol in-chain, FULL 1024-thread mm (2x2 micro-tile) ----
  {
    float* Bcol = lds;                 // 3 consecutive panels (P,W,WT)
    float* LW = lds + 3 * PANEL;
    float* Cs = lds + 4 * PANEL;
    int ty2 = tid >> 5;                // 0..31 -> rows ty2*2 + {0,1}
    int tx2 = tid & 31;                // 0..31 -> cols tx2*2 + {0,1}
    for (int j = 0; j < 3; ++j) {
      __syncthreads();
      *(float4*)&Bcol[r64 * PS + k4 * 4] =
          *(const float4*)(M + (size_t)(j * 64 + r64) * 256 + j * 64 + k4 * 4);
      __syncthreads();

      for (int i = j + 1; i < 4; ++i) {
        float acc[2][2] = {};
        for (int kk = j; kk < i; ++kk) {
          __syncthreads();
          *(float4*)&LW[r64 * PS + k4 * 4] =
              *(const float4*)(M + (size_t)(kk * 64 + r64) * 256 + i * 64 + k4 * 4);
          __syncthreads();
          float* Bk = Bcol + (kk - j) * PANEL;
#pragma unroll 4
          for (int k = 0; k < 64; ++k) {
            float2 a = *(float2*)&LW[k * PS + ty2 * 2];
            float2 b = *(float2*)&Bk[k * PS + tx2 * 2];
            acc[0][0] += a.x * b.x;
            acc[0][1] += a.x * b.y;
            acc[1][0] += a.y * b.x;
            acc[1][1] += a.y * b.y;
          }
        }
        __syncthreads();
#pragma unroll
        for (int r = 0; r < 2; ++r)
          *(float2*)&Cs[(ty2 * 2 + r) * PS + tx2 * 2] = make_float2(acc[r][0], acc[r][1]);
        {
          float4 v = *(const float4*)(M + (size_t)(i * 64 + r64) * 256 + i * 64 + k4 * 4);
          LW[(k4 * 4 + 0) * PS + r64] = v.x;
          LW[(k4 * 4 + 1) * PS + r64] = v.y;
          LW[(k4 * 4 + 2) * PS + r64] = v.z;
          LW[(k4 * 4 + 3) * PS + r64] = v.w;
        }
        __syncthreads();
        float d[2][2] = {};
#pragma unroll 4
        for (int k = 0; k < 64; ++k) {
          float2 a = *(float2*)&LW[k * PS + ty2 * 2];
          float2 b = *(float2*)&Cs[k * PS + tx2 * 2];
          d[0][0] -= a.x * b.x;
          d[0][1] -= a.x * b.y;
          d[1][0] -= a.y * b.x;
          d[1][1] -= a.y * b.y;
        }
        float* Bi = Bcol + (i - j) * PANEL;
#pragma unroll
        for (int r = 0; r < 2; ++r) {
          if (i < 3)
            *(float2*)&Bi[(ty2 * 2 + r) * PS + tx2 * 2] = make_float2(d[r][0], d[r][1]);
          uint2 pu;
          pu.x = packhl(d[r][0]);
          pu.y = packhl(d[r][1]);
          *(uint2*)(M32 + (size_t)(i * 64 + ty2 * 2 + r) * 256 + j * 64 + tx2 * 2) = pu;
        }
        __syncthreads();
      }
    }
  }
}

// maha (R8-validated): y = invL * diff, MFMA split-3, grid (s, btile).
__global__ __launch_bounds__(512) void k_maha(const float* __restrict__ x,
                                              const float* __restrict__ mu_p,
                                              const float* __restrict__ Lw,
                                              float* __restrict__ out) {
  __shared__ __align__(16) short Bh[128 * 40];
  __shared__ __align__(16) short Bl[128 * 40];
  __shared__ float Red[1025];
  int s = blockIdx.x, b0 = blockIdx.y * 128;
  const float* Mf = Lw + (size_t)s * 65536;
  const unsigned* M32 = (const unsigned*)Mf;
  int tid = threadIdx.x, w = tid >> 6, lane = tid & 63;
  int q = lane >> 4, n = lane & 15;
  int mt_[2] = {w, 15 - w};
  f32x4 acc[2][8] = {};

  for (int ks = 0; ks < 8; ++ks) {
    __syncthreads();
    {
      int b = tid >> 2, q8 = tid & 3;
      const float* xp = x + (size_t)(b0 + b) * 256 + ks * 32 + q8 * 8;
      const float* mp = mu_p + (size_t)s * 256 + ks * 32 + q8 * 8;
      float4 xa = ((const float4*)xp)[0], xb = ((const float4*)xp)[1];
      float4 ma = ((const float4*)mp)[0], mb = ((const float4*)mp)[1];
      float dv[8] = {xa.x - ma.x, xa.y - ma.y, xa.z - ma.z, xa.w - ma.w,
                     xb.x - mb.x, xb.y - mb.y, xb.z - mb.z, xb.w - mb.w};
      unsigned h[8], l[8];
#pragma unroll
      for (int jj = 0; jj < 8; ++jj) {
        h[jj] = bf16rtn(dv[jj]);
        float hf = __uint_as_float(h[jj] << 16);
        l[jj] = bf16rtn(dv[jj] - hf);
      }
      *(uint4*)&Bh[b * 40 + q8 * 8] =
          make_uint4(h[0] | (h[1] << 16), h[2] | (h[3] << 16),
                     h[4] | (h[5] << 16), h[6] | (h[7] << 16));
      *(uint4*)&Bl[b * 40 + q8 * 8] =
          make_uint4(l[0] | (l[1] << 16), l[2] | (l[3] << 16),
                     l[4] | (l[5] << 16), l[6] | (l[7] << 16));
    }
    __syncthreads();
    bf16x8 Ah[2], Al[2];
    bool act[2];
#pragma unroll
    for (int t = 0; t < 2; ++t) {
      int mt = mt_[t];
      act[t] = ks < ((mt + 2) >> 1);
      if (act[t]) {
        const unsigned* ap = M32 + (size_t)(mt * 16 + n) * 256 + ks * 32 + q * 8;
        uint4 u0 = *(const uint4*)ap;
        uint4 u1 = *(const uint4*)(ap + 4);
        unsigned uu[8] = {u0.x, u0.y, u0.z, u0.w, u1.x, u1.y, u1.z, u1.w};
        if ((ks >> 1) == (mt >> 2)) {
#pragma unroll
          for (int jj = 0; jj < 8; ++jj) {
            float f = __uint_as_float(uu[jj]);
            unsigned hh = bf16rtn(f);
            float hf = __uint_as_float(hh << 16);
            Ah[t][jj] = (short)hh;
            Al[t][jj] = (short)bf16rtn(f - hf);
          }
        } else {
#pragma unroll
          for (int jj = 0; jj < 8; ++jj) {
            Ah[t][jj] = (short)(uu[jj] >> 16);
            Al[t][jj] = (short)(uu[jj] & 0xffffu);
          }
        }
      }
    }
#pragma unroll
    for (int bsub = 0; bsub < 8; ++bsub) {
      bf16x8 bh = *(const bf16x8*)&Bh[(bsub * 16 + n) * 40 + q * 8];
      bf16x8 bl = *(const bf16x8*)&Bl[(bsub * 16 + n) * 40 + q * 8];
#pragma unroll
      for (int t = 0; t < 2; ++t) {
        if (act[t]) {
          acc[t][bsub] = __builtin_amdgcn_mfma_f32_16x16x32_bf16(Ah[t], bh, acc[t][bsub], 0, 0, 0);
          acc[t][bsub] = __builtin_amdgcn_mfma_f32_16x16x32_bf16(Ah[t], bl, acc[t][bsub], 0, 0, 0);
          acc[t][bsub] = __builtin_amdgcn_mfma_f32_16x16x32_bf16(Al[t], bh, acc[t][bsub], 0, 0, 0);
        }
      }
    }
  }
#pragma unroll
  for (int bsub = 0; bsub < 8; ++bsub) {
    float v = 0.f;
#pragma unroll
    for (int t = 0; t < 2; ++t)
#pragma unroll
      for (int r = 0; r < 4; ++r) v += acc[t][bsub][r] * acc[t][bsub][r];
    v += __shfl_xor(v, 16, 64);
    v += __shfl_xor(v, 32, 64);
    if (lane < 16) Red[w * 128 + bsub * 16 + lane] = v;
  }
  if (w == 0) {
    float ld = 0.f;
#pragma unroll
    for (int c = 0; c < 4; ++c)
      ld += logf(Mf[(size_t)(c * 64 + lane) * 256 + c * 64 + lane]);
    ld += __shfl_down(ld, 32, 64);
    ld += __shfl_down(ld, 16, 64);
    ld += __shfl_down(ld, 8, 64);
    ld += __shfl_down(ld, 4, 64);
    ld += __shfl_down(ld, 2, 64);
    ld += __shfl_down(ld, 1, 64);
    if (lane == 0) Red[1024] = ld;
  }
  __syncthreads();
  if (tid < 128) {
    float mh = 0.f;
#pragma unroll
    for (int w2 = 0; w2 < 8; ++w2) mh += Red[w2 * 128 + tid];
    out[(size_t)(b0 + tid) * 256 + s] = -0.5f * (LOG2PI_D - 2.0f * Red[1024] + mh);
  }
}

extern "C" void kernel_launch(void* const* d_in, const int* in_sizes, int n_in,
                              void* d_out, int out_size, void* d_ws, size_t ws_size,
                              hipStream_t stream) {
  const float* x = (const float*)d_in[0];
  const float* mu = (const float*)d_in[1];
  const float* sp = (const float*)d_in[2];
  float* out = (float*)d_out;
  float* L = (float*)d_ws;

  const int fact_lds = 6 * PANEL * 4;  // 104,448
  (void)hipFuncSetAttribute((const void*)k_factor,
                            hipFuncAttributeMaxDynamicSharedMemorySize, fact_lds);

  // out[s] doubles as the ridge accumulator (poison -3e-13 negligible;
  // k_maha overwrites every out element with the final logp).
  k_gram<<<dim3(256, 3), 256, 0, stream>>>(sp, L, out);
  k_factor<<<256, 1024, fact_lds, stream>>>(L, out);
  k_maha<<<dim3(256, 8), 512, 0, stream>>>(x, mu, L, out);
}

// Round 7
// 534.540 us; speedup vs baseline: 1.0887x; 1.0887x over previous
//
#include <hip/hip_runtime.h>
#include <math.h>

// B=1024, S=256, D=256 fp32.
// logp[b,s] = -0.5*(D*log2pi + logdet_s + ||L_s^{-1}(x_b-mu_s)||^2)
//
// ws: one 256x256 fp32 matrix M per s (64 MB).
//   k_gram: lower+diag = sp^T sp (MFMA split-3), grid (s,p).
//   k_factor (1024 thr, 16 waves, 104KB LDS, one block per s):
//     for kb=0..3: {ridge; rank-4 micro-Cholesky + scale; rank-8 blocked
//     forward-substitution inversion; TRSM into LDS T panels (mirror store
//     only); trail pairs read T panels (barrier-free rounds), diag pair
//     carried in P panel}; then invcol j=0..2 via MFMA split-3 with
//     gram-pattern packed h/l planes (fp32 mm was LDS-bound; R6's 2x2
//     widening doubled LDS traffic — MFMA collapses both LDS and VALU cost).
//     d goes from MFMA regs straight to packhl stores (M32 + B-panel planes).
//   k_maha: y = invL*diff via mfma split-3, grid (s, btile).

#define LOG2PI_D 470.4965290007924f  // 256*log(2*pi)
#define PS 68          // panel row stride (floats)
#define PANEL (64*68)  // panel size (floats)

typedef __attribute__((ext_vector_type(8))) short bf16x8;
typedef __attribute__((ext_vector_type(4))) float f32x4;

__device__ __forceinline__ unsigned bf16rtn(float f) {
  unsigned u = __float_as_uint(f);
  return (u + 0x7FFFu + ((u >> 16) & 1u)) >> 16;
}
__device__ __forceinline__ unsigned packhl(float v) {
  unsigned h = bf16rtn(v);
  float hf = __uint_as_float(h << 16);
  unsigned l = bf16rtn(v - hf);
  return (h << 16) | l;
}
// pack pair (v0,v1) -> h-word / l-word (low short = v0, high short = v1)
__device__ __forceinline__ void hl2(float v0, float v1, unsigned& hw, unsigned& lw) {
  unsigned h0 = bf16rtn(v0), h1 = bf16rtn(v1);
  float r0 = v0 - __uint_as_float(h0 << 16);
  float r1 = v1 - __uint_as_float(h1 << 16);
  hw = h0 | (h1 << 16);
  lw = bf16rtn(r0) | (bf16rtn(r1) << 16);
}

// Gram via MFMA split-3. Col-major scalar loads; pair-packed h/l LDS planes
// (direct bf16x8 b128 fragment reads, zero unpack). Grid (s, p).
__global__ __launch_bounds__(256) void k_gram(const float* __restrict__ sp,
                                              float* __restrict__ L,
                                              float* __restrict__ ridge_out) {
  __shared__ unsigned Hb[4 * 128 * 20];
  unsigned* AH = Hb;
  unsigned* AL = Hb + 128 * 20;
  unsigned* BH = Hb + 2 * 128 * 20;
  unsigned* BL = Hb + 3 * 128 * 20;
  int p = blockIdx.y, s = blockIdx.x;
  int bi = (p ? 128 : 0), bj = (p == 2 ? 128 : 0);
  const float* A = sp + (size_t)s * 65536;
  float* C = L + (size_t)s * 65536;
  int tid = threadIdx.x, w = tid >> 6, lane = tid & 63;
  int q = lane >> 4, n = lane & 15;
  int mt_[2] = {w, 7 - w};
  f32x4 acc[2][8] = {};
  int c = tid & 127, g = tid >> 7;

  float va[16], vb[16];
#pragma unroll
  for (int u = 0; u < 16; ++u) {
    va[u] = A[(size_t)(g * 16 + u) * 256 + bi + c];
    if (p == 1) vb[u] = A[(size_t)(g * 16 + u) * 256 + bj + c];
  }

  for (int ks = 0; ks < 8; ++ks) {
    __syncthreads();
    {
      unsigned hw[8], lw[8];
#pragma unroll
      for (int m = 0; m < 8; ++m) {
        float v0 = va[2 * m], v1 = va[2 * m + 1];
        unsigned h0 = bf16rtn(v0), h1 = bf16rtn(v1);
        float r0 = v0 - __uint_as_float(h0 << 16);
        float r1 = v1 - __uint_as_float(h1 << 16);
        hw[m] = h0 | (h1 << 16);
        lw[m] = bf16rtn(r0) | (bf16rtn(r1) << 16);
      }
      *(uint4*)&AH[c * 20 + g * 8] = make_uint4(hw[0], hw[1], hw[2], hw[3]);
      *(uint4*)&AH[c * 20 + g * 8 + 4] = make_uint4(hw[4], hw[5], hw[6], hw[7]);
      *(uint4*)&AL[c * 20 + g * 8] = make_uint4(lw[0], lw[1], lw[2], lw[3]);
      *(uint4*)&AL[c * 20 + g * 8 + 4] = make_uint4(lw[4], lw[5], lw[6], lw[7]);
      if (p == 1) {
#pragma unroll
        for (int m = 0; m < 8; ++m) {
          float v0 = vb[2 * m], v1 = vb[2 * m + 1];
          unsigned h0 = bf16rtn(v0), h1 = bf16rtn(v1);
          float r0 = v0 - __uint_as_float(h0 << 16);
          float r1 = v1 - __uint_as_float(h1 << 16);
          hw[m] = h0 | (h1 << 16);
          lw[m] = bf16rtn(r0) | (bf16rtn(r1) << 16);
        }
        *(uint4*)&BH[c * 20 + g * 8] = make_uint4(hw[0], hw[1], hw[2], hw[3]);
        *(uint4*)&BH[c * 20 + g * 8 + 4] = make_uint4(hw[4], hw[5], hw[6], hw[7]);
        *(uint4*)&BL[c * 20 + g * 8] = make_uint4(lw[0], lw[1], lw[2], lw[3]);
        *(uint4*)&BL[c * 20 + g * 8 + 4] = make_uint4(lw[4], lw[5], lw[6], lw[7]);
      }
    }
    __syncthreads();
    if (ks < 7) {
      int r0g = (ks + 1) * 32 + g * 16;
#pragma unroll
      for (int u = 0; u < 16; ++u) {
        va[u] = A[(size_t)(r0g + u) * 256 + bi + c];
        if (p == 1) vb[u] = A[(size_t)(r0g + u) * 256 + bj + c];
      }
    }
    const unsigned* TBH = (p == 1) ? BH : AH;
    const unsigned* TBL = (p == 1) ? BL : AL;
    bf16x8 Ah[2], Al[2];
#pragma unroll
    for (int t = 0; t < 2; ++t) {
      int col = mt_[t] * 16 + n;
      Ah[t] = *(const bf16x8*)&AH[col * 20 + q * 4];
      Al[t] = *(const bf16x8*)&AL[col * 20 + q * 4];
    }
    int ntmax = (p == 1) ? 8 : (8 - w);
    for (int nt = 0; nt < ntmax; ++nt) {
      bf16x8 bh = *(const bf16x8*)&TBH[(nt * 16 + n) * 20 + q * 4];
      bf16x8 bl = *(const bf16x8*)&TBL[(nt * 16 + n) * 20 + q * 4];
#pragma unroll
      for (int t = 0; t < 2; ++t) {
        if (p == 1 || nt <= mt_[t]) {
          acc[t][nt] = __builtin_amdgcn_mfma_f32_16x16x32_bf16(Ah[t], bh, acc[t][nt], 0, 0, 0);
          acc[t][nt] = __builtin_amdgcn_mfma_f32_16x16x32_bf16(Ah[t], bl, acc[t][nt], 0, 0, 0);
          acc[t][nt] = __builtin_amdgcn_mfma_f32_16x16x32_bf16(Al[t], bh, acc[t][nt], 0, 0, 0);
        }
      }
    }
  }
  if (p != 1) {
    float dsum = 0.f;
#pragma unroll
    for (int t = 0; t < 2; ++t) {
      if ((n >> 2) == q) dsum += acc[t][mt_[t]][n & 3];
    }
    dsum += __shfl_down(dsum, 32, 64);
    dsum += __shfl_down(dsum, 16, 64);
    dsum += __shfl_down(dsum, 8, 64);
    dsum += __shfl_down(dsum, 4, 64);
    dsum += __shfl_down(dsum, 2, 64);
    dsum += __shfl_down(dsum, 1, 64);
    if (lane == 0) atomicAdd(&ridge_out[s], dsum * (0.01f / 256.0f));
  }
  float* slab = (float*)Hb;
  for (int t = 0; t < 2; ++t) {
    __syncthreads();
#pragma unroll
    for (int nt = 0; nt < 8; ++nt)
#pragma unroll
      for (int r = 0; r < 4; ++r)
        slab[w * 2048 + (q * 4 + r) * 128 + nt * 16 + n] = acc[t][nt][r];
    __syncthreads();
#pragma unroll
    for (int it = 0; it < 8; ++it) {
      int idx = tid + it * 256;
      int row = idx >> 5, c4 = idx & 31;
      int wsrc = row >> 4, r16 = row & 15;
      int rt = t ? (7 - wsrc) : wsrc;
      if (p == 1 || (c4 >> 2) <= rt) {
        int d = bi + rt * 16 + r16;
        *(float4*)(C + (size_t)d * 256 + bj + c4 * 4) =
            *(float4*)&slab[wsrc * 2048 + r16 * 128 + c4 * 4];
      }
    }
  }
}

// Factor chain: one block of 1024 threads per s; T panels LDS-resident.
__global__ __launch_bounds__(1024) void k_factor(float* __restrict__ L,
                                                 const float* __restrict__ ridge_buf) {
  extern __shared__ float lds[];
  float* P = lds;
  float* W = lds + PANEL;
  float* WT = lds + 2 * PANEL;
  int s = blockIdx.x;
  float* M = L + (size_t)s * 65536;
  unsigned* M32 = (unsigned*)M;
  int tid = threadIdx.x;
  int k4 = tid & 15, r64 = tid >> 4;  // exact 64-row cover at 1024 thr
  float ridge = ridge_buf[s];

  for (int kb = 0; kb < 4; ++kb) {
    int base = kb * 64;
    __syncthreads();
    if (kb == 0)
      *(float4*)&P[r64 * PS + k4 * 4] =
          *(const float4*)(M + (size_t)(base + r64) * 256 + base + k4 * 4);
    // kb>0: P carried in LDS from previous kb's diag trail pair.
    __syncthreads();
    if (tid < 64) P[tid * PS + tid] += ridge;
    __syncthreads();
    // ---- rank-4 micro-panel factor (columns stay RAW) ----
    {
      int eo = tid & 63, ro = tid >> 6;  // ro 0..15
      for (int cb = 0; cb < 16; ++cb) {
        int c0 = cb * 4;
        float g00 = P[c0 * PS + c0];
        float g10 = P[(c0 + 1) * PS + c0], g11 = P[(c0 + 1) * PS + c0 + 1];
        float g20 = P[(c0 + 2) * PS + c0], g21 = P[(c0 + 2) * PS + c0 + 1],
              g22 = P[(c0 + 2) * PS + c0 + 2];
        float g30 = P[(c0 + 3) * PS + c0], g31 = P[(c0 + 3) * PS + c0 + 1],
              g32 = P[(c0 + 3) * PS + c0 + 2], g33 = P[(c0 + 3) * PS + c0 + 3];
        float l00 = sqrtf(g00), r0 = 1.f / l00;
        float l10 = g10 * r0, l20 = g20 * r0, l30 = g30 * r0;
        float l11 = sqrtf(g11 - l10 * l10), r1 = 1.f / l11;
        float l21 = (g21 - l20 * l10) * r1, l31 = (g31 - l30 * l10) * r1;
        float l22 = sqrtf(g22 - l20 * l20 - l21 * l21), r2 = 1.f / l22;
        float l32 = (g32 - l30 * l20 - l31 * l21) * r2;
        float l33 = sqrtf(g33 - l30 * l30 - l31 * l31 - l32 * l32), r3 = 1.f / l33;
        int e = c0 + 4 + eo;
        if (e < 64) {
          float p0 = P[e * PS + c0], p1 = P[e * PS + c0 + 1];
          float p2 = P[e * PS + c0 + 2], p3 = P[e * PS + c0 + 3];
          float le0 = p0 * r0;
          float le1 = (p1 - le0 * l10) * r1;
          float le2 = (p2 - le0 * l20 - le1 * l21) * r2;
          float le3 = (p3 - le0 * l30 - le1 * l31 - le2 * l32) * r3;
          for (int r = c0 + 4 + ro; r < 64; r += 16) {
            float q0 = P[r * PS + c0], q1 = P[r * PS + c0 + 1];
            float q2 = P[r * PS + c0 + 2], q3 = P[r * PS + c0 + 3];
            float lr0 = q0 * r0;
            float lr1 = (q1 - lr0 * l10) * r1;
            float lr2 = (q2 - lr0 * l20 - lr1 * l21) * r2;
            float lr3 = (q3 - lr0 * l30 - lr1 * l31 - lr2 * l32) * r3;
            P[r * PS + e] -= lr0 * le0 + lr1 * le1 + lr2 * le2 + lr3 * le3;
          }
        }
        __syncthreads();
      }
    }
    // ---- scale pass ----
    {
      int cb = tid >> 4, lane16 = tid & 15;
      int c0 = cb * 4;
      float vals[4][4];
      int rows[4], nr = 0;
      if (tid < 256) {
        float g00 = P[c0 * PS + c0];
        float g10 = P[(c0 + 1) * PS + c0], g11 = P[(c0 + 1) * PS + c0 + 1];
        float g20 = P[(c0 + 2) * PS + c0], g21 = P[(c0 + 2) * PS + c0 + 1],
              g22 = P[(c0 + 2) * PS + c0 + 2];
        float g30 = P[(c0 + 3) * PS + c0], g31 = P[(c0 + 3) * PS + c0 + 1],
              g32 = P[(c0 + 3) * PS + c0 + 2], g33 = P[(c0 + 3) * PS + c0 + 3];
        float l00 = sqrtf(g00), r0 = 1.f / l00;
        float l10 = g10 * r0, l20 = g20 * r0, l30 = g30 * r0;
        float l11 = sqrtf(g11 - l10 * l10), r1 = 1.f / l11;
        float l21 = (g21 - l20 * l10) * r1, l31 = (g31 - l30 * l10) * r1;
        float l22 = sqrtf(g22 - l20 * l20 - l21 * l21), r2 = 1.f / l22;
        float l32 = (g32 - l30 * l20 - l31 * l21) * r2;
        float l33 = sqrtf(g33 - l30 * l30 - l31 * l31 - l32 * l32), r3 = 1.f / l33;
        for (int r = c0 + lane16; r < 64; r += 16) {
          int i = r - c0;
          if (i == 0) { vals[nr][0] = l00; vals[nr][1] = 0; vals[nr][2] = 0; vals[nr][3] = 0; }
          else if (i == 1) { vals[nr][0] = l10; vals[nr][1] = l11; vals[nr][2] = 0; vals[nr][3] = 0; }
          else if (i == 2) { vals[nr][0] = l20; vals[nr][1] = l21; vals[nr][2] = l22; vals[nr][3] = 0; }
          else if (i == 3) { vals[nr][0] = l30; vals[nr][1] = l31; vals[nr][2] = l32; vals[nr][3] = l33; }
          else {
            float q0 = P[r * PS + c0], q1 = P[r * PS + c0 + 1];
            float q2 = P[r * PS + c0 + 2], q3 = P[r * PS + c0 + 3];
            float lr0 = q0 * r0;
            float lr1 = (q1 - lr0 * l10) * r1;
            float lr2 = (q2 - lr0 * l20 - lr1 * l21) * r2;
            float lr3 = (q3 - lr0 * l30 - lr1 * l31 - lr2 * l32) * r3;
            vals[nr][0] = lr0; vals[nr][1] = lr1; vals[nr][2] = lr2; vals[nr][3] = lr3;
          }
          rows[nr++] = r;
        }
      }
      __syncthreads();
      if (tid < 256) {
        for (int u = 0; u < nr; ++u) {
          int r = rows[u];
          P[r * PS + c0] = vals[u][0];
          P[r * PS + c0 + 1] = vals[u][1];
          P[r * PS + c0 + 2] = vals[u][2];
          P[r * PS + c0 + 3] = vals[u][3];
        }
      }
    }
    __syncthreads();
    // ---- rank-8 blocked forward-substitution inversion: W = inv(P_lower) ----
    for (int idx = tid; idx < PANEL; idx += 1024) W[idx] = 0.f;
    __syncthreads();
    for (int r8 = 0; r8 < 8; ++r8) {
      int k0 = r8 * 8;
      if (tid < 512) {
        int i = tid >> 6, cc = tid & 63;
        int row = k0 + i;
        float ss = 0.f;
        for (int k = 0; k < k0; ++k) ss += P[row * PS + k] * W[k * PS + cc];
        WT[i * PS + cc] = ss;  // WT rows 0..7 as S scratch
      }
      __syncthreads();
      if (tid < 64) {
        int cc = tid;
        float x[8];
#pragma unroll
        for (int m = 0; m < 8; ++m) {
          float v = ((cc == k0 + m) ? 1.f : 0.f) - WT[m * PS + cc];
#pragma unroll
          for (int u = 0; u < 8; ++u)
            if (u < m) v -= P[(k0 + m) * PS + k0 + u] * x[u];
          x[m] = v / P[(k0 + m) * PS + k0 + m];
          W[(k0 + m) * PS + cc] = x[m];
        }
      }
      __syncthreads();
    }
    // WT = W^T (full overwrite of scratch)
    {
      float4 v = *(float4*)&W[r64 * PS + k4 * 4];
      WT[(k4 * 4 + 0) * PS + r64] = v.x;
      WT[(k4 * 4 + 1) * PS + r64] = v.y;
      WT[(k4 * 4 + 2) * PS + r64] = v.z;
      WT[(k4 * 4 + 3) * PS + r64] = v.w;
    }
    __syncthreads();
    // store W (diag block) to M — consumed by invcol + maha
    *(float4*)(M + (size_t)(base + r64) * 256 + base + k4 * 4) = *(float4*)&W[r64 * PS + k4 * 4];
    // ---- TRSM: tiles into LDS T panels; mirror store only ----
    int nrt = 3 - kb;
    for (int rt0 = 0; rt0 < nrt; rt0 += 2) {
      int pr = tid >> 9, t2 = tid & 511;
      int my = rt0 + pr;
      bool act = my < nrt;
      float* Tb = lds + (size_t)(3 + (act ? my : 0)) * PANEL;
      int k42 = t2 & 15, rbl = t2 >> 4;
      int ty2 = t2 >> 4, tx2 = t2 & 15;
      int g0 = base + 64 + my * 64;
      __syncthreads();
      if (act) {
#pragma unroll
        for (int r = rbl; r < 64; r += 32) {
          float4 v = *(const float4*)(M + (size_t)(g0 + r) * 256 + base + k42 * 4);
          Tb[(k42 * 4 + 0) * PS + r] = v.x;
          Tb[(k42 * 4 + 1) * PS + r] = v.y;
          Tb[(k42 * 4 + 2) * PS + r] = v.z;
          Tb[(k42 * 4 + 3) * PS + r] = v.w;
        }
      }
      __syncthreads();
      float acc[2][4] = {};
      if (act) {
        for (int k = 0; k < 64; ++k) {
          float a0 = Tb[k * PS + ty2 * 2], a1 = Tb[k * PS + ty2 * 2 + 1];
          float b[4];
          *(float4*)b = *(float4*)&WT[k * PS + tx2 * 4];
#pragma unroll
          for (int j = 0; j < 4; ++j) {
            acc[0][j] += a0 * b[j];
            acc[1][j] += a1 * b[j];
          }
        }
      }
      __syncthreads();
      if (act) {
        // overwrite Tb with L^T layout [k][m] (trail operand + mirror source)
#pragma unroll
        for (int i = 0; i < 2; ++i)
#pragma unroll
          for (int j = 0; j < 4; ++j) Tb[(tx2 * 4 + j) * PS + ty2 * 2 + i] = acc[i][j];
      }
      __syncthreads();
      if (act) {
#pragma unroll
        for (int r = rbl; r < 64; r += 32)
          *(float4*)(M + (size_t)(base + r) * 256 + g0 + k42 * 4) = *(float4*)&Tb[r * PS + k42 * 4];
      }
      // (row-major lower store dropped — dead: trail reads LDS, maha reads packed)
    }
    __syncthreads();
    // ---- trailing updates: read T panels, barrier-free rounds ----
    int np = ((3 - kb) * (4 - kb)) / 2;
    for (int p0 = 0; p0 < np; p0 += 2) {
      int pr = tid >> 9, t2 = tid & 511;
      int my = p0 + pr;
      bool act = my < np;
      int ti = kb + 1, tj = kb + 1;
      {
        int cnt = 0;
        for (int a = kb + 1; a < 4; ++a)
          for (int b = kb + 1; b <= a; ++b) {
            if (cnt == my) { ti = a; tj = b; }
            ++cnt;
          }
      }
      float* Pi = lds + (size_t)(3 + (ti - kb - 1)) * PANEL;
      float* Pj = lds + (size_t)(3 + (tj - kb - 1)) * PANEL;
      int ty2 = t2 >> 4, tx2 = t2 & 15;
      float acc[2][4];
      if (act) {
#pragma unroll
        for (int i = 0; i < 2; ++i)
          *(float4*)&acc[i][0] =
              *(const float4*)(M + (size_t)(ti * 64 + ty2 * 2 + i) * 256 + tj * 64 + tx2 * 4);
        for (int k = 0; k < 64; ++k) {
          float a0 = Pi[k * PS + ty2 * 2], a1 = Pi[k * PS + ty2 * 2 + 1];
          float b[4];
          *(float4*)b = *(float4*)&Pj[k * PS + tx2 * 4];
#pragma unroll
          for (int j = 0; j < 4; ++j) {
            acc[0][j] -= a0 * b[j];
            acc[1][j] -= a1 * b[j];
          }
        }
        if (ti == tj && ti == kb + 1) {
          // next panel: carry in P (LDS), skip dead M store
#pragma unroll
          for (int i = 0; i < 2; ++i)
            *(float4*)&P[(ty2 * 2 + i) * PS + tx2 * 4] =
                make_float4(acc[i][0], acc[i][1], acc[i][2], acc[i][3]);
        } else {
#pragma unroll
          for (int i = 0; i < 2; ++i)
            *(float4*)(M + (size_t)(ti * 64 + ty2 * 2 + i) * 256 + tj * 64 + tx2 * 4) =
                make_float4(acc[i][0], acc[i][1], acc[i][2], acc[i][3]);
        }
      }
    }
  }

  // ---- invcol via MFMA split-3 (gram-pattern packed planes) ----
  // For j<3, i>j: C = sum_kk Lt(kk,i) x B(kk)  [A-planes x B-planes];
  // d = -Wd_i x C  [A2-planes x C-planes]; packhl(d) -> M32 (+B panel i-j).
  // Plane pair p at U + p*4608 u32: H plane [64 col][36], L at +2304.
  // pairs 0..2 = B panels, 3 = A (Lt / Wd_i), 4 = C.
  {
    unsigned* U = (unsigned*)lds;
    const int ST = 36, HL = 2304, PP = 4608;
    const int PA = 3 * PP, PC = 4 * PP;
    int lane = tid & 63, wv = tid >> 6;
    int q = lane >> 4, n = lane & 15;
    int wr = wv >> 2, wc = wv & 3;
    int pc = tid & 63, pg = tid >> 6;  // pack ownership: col pc, k = pg*4..+3
    int colA = wr * 16 + n, colB = wc * 16 + n;

    for (int j = 0; j < 3; ++j) {
      __syncthreads();
      {  // pack B0 = Wd_j : B[k][c] = M[(j*64+k)][j*64+c]
        float v0 = M[(size_t)(j * 64 + pg * 4 + 0) * 256 + j * 64 + pc];
        float v1 = M[(size_t)(j * 64 + pg * 4 + 1) * 256 + j * 64 + pc];
        float v2 = M[(size_t)(j * 64 + pg * 4 + 2) * 256 + j * 64 + pc];
        float v3 = M[(size_t)(j * 64 + pg * 4 + 3) * 256 + j * 64 + pc];
        unsigned hw, lw;
        hl2(v0, v1, hw, lw);
        U[pc * ST + 2 * pg] = hw; U[HL + pc * ST + 2 * pg] = lw;
        hl2(v2, v3, hw, lw);
        U[pc * ST + 2 * pg + 1] = hw; U[HL + pc * ST + 2 * pg + 1] = lw;
      }
      for (int i = j + 1; i < 4; ++i) {
        f32x4 a1 = {0.f, 0.f, 0.f, 0.f};
        for (int kk = j; kk < i; ++kk) {
          __syncthreads();
          {  // pack A = Lt(kk,i): A[k][r] = M[(kk*64+k)][i*64+r] (mirror)
            float v0 = M[(size_t)(kk * 64 + pg * 4 + 0) * 256 + i * 64 + pc];
            float v1 = M[(size_t)(kk * 64 + pg * 4 + 1) * 256 + i * 64 + pc];
            float v2 = M[(size_t)(kk * 64 + pg * 4 + 2) * 256 + i * 64 + pc];
            float v3 = M[(size_t)(kk * 64 + pg * 4 + 3) * 256 + i * 64 + pc];
            unsigned hw, lw;
            hl2(v0, v1, hw, lw);
            U[PA + pc * ST + 2 * pg] = hw; U[PA + HL + pc * ST + 2 * pg] = lw;
            hl2(v2, v3, hw, lw);
            U[PA + pc * ST + 2 * pg + 1] = hw; U[PA + HL + pc * ST + 2 * pg + 1] = lw;
          }
          __syncthreads();
          int PB = (kk - j) * PP;
#pragma unroll
          for (int ks = 0; ks < 2; ++ks) {
            bf16x8 Ah = *(const bf16x8*)&U[PA + colA * ST + ks * 16 + q * 4];
            bf16x8 Al = *(const bf16x8*)&U[PA + HL + colA * ST + ks * 16 + q * 4];
            bf16x8 Bh = *(const bf16x8*)&U[PB + colB * ST + ks * 16 + q * 4];
            bf16x8 Bl = *(const bf16x8*)&U[PB + HL + colB * ST + ks * 16 + q * 4];
            a1 = __builtin_amdgcn_mfma_f32_16x16x32_bf16(Ah, Bh, a1, 0, 0, 0);
            a1 = __builtin_amdgcn_mfma_f32_16x16x32_bf16(Ah, Bl, a1, 0, 0, 0);
            a1 = __builtin_amdgcn_mfma_f32_16x16x32_bf16(Al, Bh, a1, 0, 0, 0);
          }
        }
        __syncthreads();
        {  // pack A2 = Wd_i (transposed): A2[k][r] = M[(i*64+r)][i*64+k]
          float4 v = *(const float4*)(M + (size_t)(i * 64 + pc) * 256 + i * 64 + pg * 4);
          unsigned hw, lw;
          hl2(v.x, v.y, hw, lw);
          U[PA + pc * ST + 2 * pg] = hw; U[PA + HL + pc * ST + 2 * pg] = lw;
          hl2(v.z, v.w, hw, lw);
          U[PA + pc * ST + 2 * pg + 1] = hw; U[PA + HL + pc * ST + 2 * pg + 1] = lw;
        }
        {  // pack C from a1: lane holds col colB, rows wr*16+q*4+{0..3}
          unsigned hw, lw;
          hl2(a1[0], a1[1], hw, lw);
          U[PC + colB * ST + wr * 8 + 2 * q] = hw;
          U[PC + HL + colB * ST + wr * 8 + 2 * q] = lw;
          hl2(a1[2], a1[3], hw, lw);
          U[PC + colB * ST + wr * 8 + 2 * q + 1] = hw;
          U[PC + HL + colB * ST + wr * 8 + 2 * q + 1] = lw;
        }
        __syncthreads();
        f32x4 a2 = {0.f, 0.f, 0.f, 0.f};
#pragma unroll
        for (int ks = 0; ks < 2; ++ks) {
          bf16x8 Ah = *(const bf16x8*)&U[PA + colA * ST + ks * 16 + q * 4];
          bf16x8 Al = *(const bf16x8*)&U[PA + HL + colA * ST + ks * 16 + q * 4];
          bf16x8 Bh = *(const bf16x8*)&U[PC + colB * ST + ks * 16 + q * 4];
          bf16x8 Bl = *(const bf16x8*)&U[PC + HL + colB * ST + ks * 16 + q * 4];
          a2 = __builtin_amdgcn_mfma_f32_16x16x32_bf16(Ah, Bh, a2, 0, 0, 0);
          a2 = __builtin_amdgcn_mfma_f32_16x16x32_bf16(Ah, Bl, a2, 0, 0, 0);
          a2 = __builtin_amdgcn_mfma_f32_16x16x32_bf16(Al, Bh, a2, 0, 0, 0);
        }
        float dv[4] = {-a2[0], -a2[1], -a2[2], -a2[3]};
#pragma unroll
        for (int r = 0; r < 4; ++r)
          M32[(size_t)(i * 64 + wr * 16 + q * 4 + r) * 256 + j * 64 + colB] = packhl(dv[r]);
        if (i < 3) {  // pack d into B panel (i-j) for later kk consumption
          int PB = (i - j) * PP;
          unsigned hw, lw;
          hl2(dv[0], dv[1], hw, lw);
          U[PB + colB * ST + wr * 8 + 2 * q] = hw;
          U[PB + HL + colB * ST + wr * 8 + 2 * q] = lw;
          hl2(dv[2], dv[3], hw, lw);
          U[PB + colB * ST + wr * 8 + 2 * q + 1] = hw;
          U[PB + HL + colB * ST + wr * 8 + 2 * q + 1] = lw;
        }
      }
    }
  }
}

// maha (R8-validated): y = invL * diff, MFMA split-3, grid (s, btile).
__global__ __launch_bounds__(512) void k_maha(const float* __restrict__ x,
                                              const float* __restrict__ mu_p,
                                              const float* __restrict__ Lw,
                                              float* __restrict__ out) {
  __shared__ __align__(16) short Bh[128 * 40];
  __shared__ __align__(16) short Bl[128 * 40];
  __shared__ float Red[1025];
  int s = blockIdx.x, b0 = blockIdx.y * 128;
  const float* Mf = Lw + (size_t)s * 65536;
  const unsigned* M32 = (const unsigned*)Mf;
  int tid = threadIdx.x, w = tid >> 6, lane = tid & 63;
  int q = lane >> 4, n = lane & 15;
  int mt_[2] = {w, 15 - w};
  f32x4 acc[2][8] = {};

  for (int ks = 0; ks < 8; ++ks) {
    __syncthreads();
    {
      int b = tid >> 2, q8 = tid & 3;
      const float* xp = x + (size_t)(b0 + b) * 256 + ks * 32 + q8 * 8;
      const float* mp = mu_p + (size_t)s * 256 + ks * 32 + q8 * 8;
      float4 xa = ((const float4*)xp)[0], xb = ((const float4*)xp)[1];
      float4 ma = ((const float4*)mp)[0], mb = ((const float4*)mp)[1];
      float dv[8] = {xa.x - ma.x, xa.y - ma.y, xa.z - ma.z, xa.w - ma.w,
                     xb.x - mb.x, xb.y - mb.y, xb.z - mb.z, xb.w - mb.w};
      unsigned h[8], l[8];
#pragma unroll
      for (int jj = 0; jj < 8; ++jj) {
        h[jj] = bf16rtn(dv[jj]);
        float hf = __uint_as_float(h[jj] << 16);
        l[jj] = bf16rtn(dv[jj] - hf);
      }
      *(uint4*)&Bh[b * 40 + q8 * 8] =
          make_uint4(h[0] | (h[1] << 16), h[2] | (h[3] << 16),
                     h[4] | (h[5] << 16), h[6] | (h[7] << 16));
      *(uint4*)&Bl[b * 40 + q8 * 8] =
          make_uint4(l[0] | (l[1] << 16), l[2] | (l[3] << 16),
                     l[4] | (l[5] << 16), l[6] | (l[7] << 16));
    }
    __syncthreads();
    bf16x8 Ah[2], Al[2];
    bool act[2];
#pragma unroll
    for (int t = 0; t < 2; ++t) {
      int mt = mt_[t];
      act[t] = ks < ((mt + 2) >> 1);
      if (act[t]) {
        const unsigned* ap = M32 + (size_t)(mt * 16 + n) * 256 + ks * 32 + q * 8;
        uint4 u0 = *(const uint4*)ap;
        uint4 u1 = *(const uint4*)(ap + 4);
        unsigned uu[8] = {u0.x, u0.y, u0.z, u0.w, u1.x, u1.y, u1.z, u1.w};
        if ((ks >> 1) == (mt >> 2)) {
#pragma unroll
          for (int jj = 0; jj < 8; ++jj) {
            float f = __uint_as_float(uu[jj]);
            unsigned hh = bf16rtn(f);
            float hf = __uint_as_float(hh << 16);
            Ah[t][jj] = (short)hh;
            Al[t][jj] = (short)bf16rtn(f - hf);
          }
        } else {
#pragma unroll
          for (int jj = 0; jj < 8; ++jj) {
            Ah[t][jj] = (short)(uu[jj] >> 16);
            Al[t][jj] = (short)(uu[jj] & 0xffffu);
          }
        }
      }
    }
#pragma unroll
    for (int bsub = 0; bsub < 8; ++bsub) {
      bf16x8 bh = *(const bf16x8*)&Bh[(bsub * 16 + n) * 40 + q * 8];
      bf16x8 bl = *(const bf16x8*)&Bl[(bsub * 16 + n) * 40 + q * 8];
#pragma unroll
      for (int t = 0; t < 2; ++t) {
        if (act[t]) {
          acc[t][bsub] = __builtin_amdgcn_mfma_f32_16x16x32_bf16(Ah[t], bh, acc[t][bsub], 0, 0, 0);
          acc[t][bsub] = __builtin_amdgcn_mfma_f32_16x16x32_bf16(Ah[t], bl, acc[t][bsub], 0, 0, 0);
          acc[t][bsub] = __builtin_amdgcn_mfma_f32_16x16x32_bf16(Al[t], bh, acc[t][bsub], 0, 0, 0);
        }
      }
    }
  }
#pragma unroll
  for (int bsub = 0; bsub < 8; ++bsub) {
    float v = 0.f;
#pragma unroll
    for (int t = 0; t < 2; ++t)
#pragma unroll
      for (int r = 0; r < 4; ++r) v += acc[t][bsub][r] * acc[t][bsub][r];
    v += __shfl_xor(v, 16, 64);
    v += __shfl_xor(v, 32, 64);
    if (lane < 16) Red[w * 128 + bsub * 16 + lane] = v;
  }
  if (w == 0) {
    float ld = 0.f;
#pragma unroll
    for (int c = 0; c < 4; ++c)
      ld += logf(Mf[(size_t)(c * 64 + lane) * 256 + c * 64 + lane]);
    ld += __shfl_down(ld, 32, 64);
    ld += __shfl_down(ld, 16, 64);
    ld += __shfl_down(ld, 8, 64);
    ld += __shfl_down(ld, 4, 64);
    ld += __shfl_down(ld, 2, 64);
    ld += __shfl_down(ld, 1, 64);
    if (lane == 0) Red[1024] = ld;
  }
  __syncthreads();
  if (tid < 128) {
    float mh = 0.f;
#pragma unroll
    for (int w2 = 0; w2 < 8; ++w2) mh += Red[w2 * 128 + tid];
    out[(size_t)(b0 + tid) * 256 + s] = -0.5f * (LOG2PI_D - 2.0f * Red[1024] + mh);
  }
}

extern "C" void kernel_launch(void* const* d_in, const int* in_sizes, int n_in,
                              void* d_out, int out_size, void* d_ws, size_t ws_size,
                              hipStream_t stream) {
  const float* x = (const float*)d_in[0];
  const float* mu = (const float*)d_in[1];
  const float* sp = (const float*)d_in[2];
  float* out = (float*)d_out;
  float* L = (float*)d_ws;

  const int fact_lds = 6 * PANEL * 4;  // 104,448
  (void)hipFuncSetAttribute((const void*)k_factor,
                            hipFuncAttributeMaxDynamicSharedMemorySize, fact_lds);

  // out[s] doubles as the ridge accumulator (poison -3e-13 negligible;
  // k_maha overwrites every out element with the final logp).
  k_gram<<<dim3(256, 3), 256, 0, stream>>>(sp, L, out);
  k_factor<<<256, 1024, fact_lds, stream>>>(L, out);
  k_maha<<<dim3(256, 8), 512, 0, stream>>>(x, mu, L, out);
}